// Round 7
// baseline (258.395 us; speedup 1.0000x reference)
//
#include <hip/hip_runtime.h>
#include <hip/hip_fp16.h>

#define N_NODES 50000
#define N_EDGES 800000
#define D_IN 64
#define MAXD 64
#define BSHIFT 7                       // 128 nodes per bucket
#define BNODES 128
#define NBUCKET 391                    // ceil(50000/128)
#define NSCB 256                       // hist/scatter blocks
#define EPB (N_EDGES / NSCB)           // 3125 edges per block
#define NENT (NBUCKET * NSCB)          // 100096 (bucket-major)
#define LD4(p) (*(const float4*)(p))

__device__ __forceinline__ float2 up2(unsigned int u) {
    return __half22float2(*(__half2*)&u);
}
__device__ __forceinline__ unsigned int pk2(float lo, float hi) {
    __half2 h = __floats2half2_rn(lo, hi);
    return *(unsigned int*)&h;
}

// ---- K0: node linears: xw1n = x@w1n ; xr1b = x@w1r + b1 (fp16 out) ----
__global__ __launch_bounds__(256) void k_lin1(
        const float* __restrict__ x,
        const float* __restrict__ w1n, const float* __restrict__ w1r,
        const float* __restrict__ b1,
        __half* __restrict__ xw1n, __half* __restrict__ xr1b) {
    __shared__ float wn[1024], wr[1024], bs[16];
    for (int i = threadIdx.x; i < 1024; i += 256) { wn[i] = w1n[i]; wr[i] = w1r[i]; }
    if (threadIdx.x < 16) bs[threadIdx.x] = b1[threadIdx.x];
    __syncthreads();
    const int t = blockIdx.x * 256 + threadIdx.x;   // 800000 threads exactly
    const int node = t >> 4, f = t & 15;
    const float* xr = x + node * D_IN;
    float an = 0.f, ar = bs[f];
#pragma unroll
    for (int k = 0; k < D_IN; ++k) {
        float xv = xr[k];
        an += xv * wn[k * 16 + f];
        ar += xv * wr[k * 16 + f];
    }
    xw1n[t] = __float2half(an);
    xr1b[t] = __float2half(ar);
}

// ---- K1: per-block bucket histogram ----
__global__ __launch_bounds__(256) void k_hist(const int* __restrict__ dst,
                                              int* __restrict__ ghist) {
    __shared__ int lh[NBUCKET];
    for (int i = threadIdx.x; i < NBUCKET; i += 256) lh[i] = 0;
    __syncthreads();
    const int base = blockIdx.x * EPB;
    for (int i = threadIdx.x; i < EPB; i += 256)
        atomicAdd(&lh[dst[base + i] >> BSHIFT], 1);
    __syncthreads();
    for (int i = threadIdx.x; i < NBUCKET; i += 256)
        ghist[i * NSCB + blockIdx.x] = lh[i];        // bucket-major
}

// ---- K2: exclusive scan of ghist (one block) + bucket starts ----
__global__ __launch_bounds__(256) void k_scan(const int* __restrict__ ghist,
                                              int* __restrict__ gscan,
                                              int* __restrict__ bucketStart) {
    __shared__ int s[256];
    const int t = threadIdx.x;
    const int PER = (NENT + 255) / 256;              // 391
    const int lo = t * PER, hi = min(lo + PER, NENT);
    int sum = 0;
    for (int i = lo; i < hi; ++i) sum += ghist[i];
    s[t] = sum;
    __syncthreads();
    for (int d = 1; d < 256; d <<= 1) {
        int v = (t >= d) ? s[t - d] : 0;
        __syncthreads();
        s[t] += v;
        __syncthreads();
    }
    int run = s[t] - sum;                            // exclusive
    for (int i = lo; i < hi; ++i) {
        int v = ghist[i];
        gscan[i] = run;
        if ((i & (NSCB - 1)) == 0) bucketStart[i >> 8] = run;
        run += v;
    }
    if (t == 0) bucketStart[NBUCKET] = N_EDGES;
}

// ---- K3: scatter edges into bucket-grouped staging (packed u32) ----
__global__ __launch_bounds__(256) void k_scatter(const int* __restrict__ src,
                                                 const int* __restrict__ dst,
                                                 const int* __restrict__ gscan,
                                                 unsigned int* __restrict__ staging) {
    __shared__ int cur[NBUCKET];
    for (int i = threadIdx.x; i < NBUCKET; i += 256)
        cur[i] = gscan[i * NSCB + blockIdx.x];
    __syncthreads();
    const int base = blockIdx.x * EPB;
    for (int i = threadIdx.x; i < EPB; i += 256) {
        int d = dst[base + i], s = src[base + i];
        int pos = atomicAdd(&cur[d >> BSHIFT], 1);
        staging[pos] = ((unsigned int)(d & (BNODES - 1)) << 16) | (unsigned int)s;
    }
}

// ---- K4: per-bucket padded-table build in LDS, coalesced write-out ----
__global__ __launch_bounds__(256) void k_build(const unsigned int* __restrict__ staging,
                                               const int* __restrict__ bucketStart,
                                               unsigned int* __restrict__ nbrU,
                                               int* __restrict__ deg) {
    __shared__ unsigned short ltbl[BNODES * MAXD];
    __shared__ int lcnt[BNODES];
    const int tid = threadIdx.x, b = blockIdx.x;
    if (tid < BNODES) lcnt[tid] = 0;
    __syncthreads();
    const int beg = bucketStart[b], end = bucketStart[b + 1];
    for (int i = beg + tid; i < end; i += 256) {
        unsigned int u = staging[i];
        int dl = u >> 16, s = u & 0xFFFF;
        int slot = atomicAdd(&lcnt[dl], 1);
        if (slot < MAXD) ltbl[(dl << 6) + slot] = (unsigned short)s;
    }
    __syncthreads();
    const int nbase = b << BSHIFT;
    for (int i = tid; i < BNODES * 32; i += 256) {
        int nl = i >> 5, j = i & 31;
        int node = nbase + nl;
        if (node < N_NODES && 2 * j < lcnt[nl]) {
            unsigned int lo = ltbl[(nl << 6) + 2 * j];
            unsigned int hi = ltbl[(nl << 6) + 2 * j + 1];
            nbrU[(node << 5) + j] = lo | (hi << 16);
        }
    }
    if (tid < BNODES && nbase + tid < N_NODES) deg[nbase + tid] = lcnt[tid];
}

// ---- K5: h1 = relu(mean_nbrs(xw1n) + xr1b) ----
__global__ __launch_bounds__(256) void k_agg1(
        const __half* __restrict__ xw1n, const __half* __restrict__ xr1b,
        const int* __restrict__ deg, const unsigned short* __restrict__ nbr,
        __half* __restrict__ h1) {
    const int t = blockIdx.x * 256 + threadIdx.x;
    if (t >= N_NODES * 16) return;
    const int node = t >> 4, f = t & 15;
    int c = deg[node];
    float inv = c > 0 ? 1.f / (float)c : 1.f;
    int cc = c > MAXD ? MAXD : c;
    const unsigned short* np = nbr + (node << 6);
    float a0 = 0.f, a1 = 0.f, a2 = 0.f, a3 = 0.f;
    int j = 0;
    for (; j + 4 <= cc; j += 4) {
        int s0 = np[j], s1 = np[j + 1], s2 = np[j + 2], s3 = np[j + 3];
        a0 += __half2float(xw1n[(s0 << 4) + f]);
        a1 += __half2float(xw1n[(s1 << 4) + f]);
        a2 += __half2float(xw1n[(s2 << 4) + f]);
        a3 += __half2float(xw1n[(s3 << 4) + f]);
    }
    for (; j < cc; ++j) a0 += __half2float(xw1n[(np[j] << 4) + f]);
    h1[t] = __float2half(fmaxf((a0 + a1 + a2 + a3) * inv + __half2float(xr1b[t]), 0.f));
}

// ---- K6: agg2 = mean_nbrs(h1)  (fp16 out) ----
__global__ __launch_bounds__(256) void k_agg2(
        const __half* __restrict__ h1,
        const int* __restrict__ deg, const unsigned short* __restrict__ nbr,
        __half* __restrict__ agg2) {
    const int t = blockIdx.x * 256 + threadIdx.x;
    if (t >= N_NODES * 16) return;
    const int node = t >> 4, f = t & 15;
    int c = deg[node];
    float inv = c > 0 ? 1.f / (float)c : 1.f;
    int cc = c > MAXD ? MAXD : c;
    const unsigned short* np = nbr + (node << 6);
    float a0 = 0.f, a1 = 0.f, a2 = 0.f, a3 = 0.f;
    int j = 0;
    for (; j + 4 <= cc; j += 4) {
        int s0 = np[j], s1 = np[j + 1], s2 = np[j + 2], s3 = np[j + 3];
        a0 += __half2float(h1[(s0 << 4) + f]);
        a1 += __half2float(h1[(s1 << 4) + f]);
        a2 += __half2float(h1[(s2 << 4) + f]);
        a3 += __half2float(h1[(s3 << 4) + f]);
    }
    for (; j < cc; ++j) a0 += __half2float(h1[(np[j] << 4) + f]);
    agg2[t] = __float2half((a0 + a1 + a2 + a3) * inv);
}

// ---- K7 (k_head): pure dense SAGE2 + MLP head; fp16-packed fw1/fw2 ----
// 4 lanes per node, 64 nodes per 256-thread block. LDS ~27KB.
__global__ __launch_bounds__(256) void k_head(
        const __half* __restrict__ h1, const __half* __restrict__ agg2,
        const float* __restrict__ w2n, const float* __restrict__ w2r,
        const float* __restrict__ b2,
        const float* __restrict__ fw1, const float* __restrict__ fb1,
        const float* __restrict__ fw2, const float* __restrict__ fb2,
        const float* __restrict__ fw3, const float* __restrict__ fb3,
        float* __restrict__ out) {
    __shared__ __align__(16) float s_w2n[512];
    __shared__ __align__(16) float s_w2r[512];
    __shared__ __align__(16) unsigned int s_fw1u[1024];      // [k][32 half2]
    __shared__ __align__(16) unsigned int s_fw2u[4 * 1032];  // [q][k][16 half2]+pad8
    __shared__ __align__(16) float s_fw3[256];
    __shared__ __align__(16) float s_b2[32];
    __shared__ __align__(16) float s_fb1[64];
    __shared__ __align__(16) float s_fb2[128];
    __shared__ float s_fb3[2];

    const int tid = threadIdx.x;
    for (int i = tid; i < 512; i += 256) { s_w2n[i] = w2n[i]; s_w2r[i] = w2r[i]; }
    for (int i = tid; i < 1024; i += 256) {                  // fw1 [32x64] -> half2
        int k = i >> 5, p = i & 31;
        s_fw1u[k * 32 + p] = pk2(fw1[k * 64 + 2 * p], fw1[k * 64 + 2 * p + 1]);
    }
    for (int i = tid; i < 4096; i += 256) {                  // fw2 [64x128] -> half2
        int k = i >> 6, p = i & 63;
        s_fw2u[(p >> 4) * 1032 + k * 16 + (p & 15)] =
            pk2(fw2[k * 128 + 2 * p], fw2[k * 128 + 2 * p + 1]);
    }
    s_fw3[tid] = fw3[tid & 255];
    if (tid < 32) s_b2[tid] = b2[tid];
    if (tid < 64) s_fb1[tid] = fb1[tid];
    if (tid < 128) s_fb2[tid] = fb2[tid];
    if (tid < 2) s_fb3[tid] = fb3[tid];
    __syncthreads();

    const int nl = tid >> 2;             // node local 0..63
    const int q  = tid & 3;              // quarter lane
    const int node = blockIdx.x * 64 + nl;
    const int nodec = node < N_NODES ? node : (N_NODES - 1);
    const int qbase = (tid & 63) & ~3;   // quad base lane in wave

    // z slices: za = agg2 feats q*4..+3, zh = h1 feats q*4..+3 (dense reads)
    float za[4], zh[4];
    {
        const __half2* ap = (const __half2*)(agg2 + (nodec << 4) + (q << 2));
        const __half2* hp = (const __half2*)(h1 + (nodec << 4) + (q << 2));
        float2 v0 = __half22float2(ap[0]), v1 = __half22float2(ap[1]);
        za[0] = v0.x; za[1] = v0.y; za[2] = v1.x; za[3] = v1.y;
        float2 w0 = __half22float2(hp[0]), w1 = __half22float2(hp[1]);
        zh[0] = w0.x; zh[1] = w0.y; zh[2] = w1.x; zh[3] = w1.y;
    }

    // ---- h2 = relu(agg@w2n + h1@w2r + b2): f-slice 8 (f0 = q*8) ----
    float h2r[8];
    {
        const int f0 = q * 8;
        float4 accA = LD4(s_b2 + f0), accB = LD4(s_b2 + f0 + 4);
#pragma unroll
        for (int k = 0; k < 16; ++k) {
            int sl = qbase + (k >> 2);
            float zn = __shfl(za[k & 3], sl);
            float zr = __shfl(zh[k & 3], sl);
            float4 wnA = LD4(s_w2n + k * 32 + f0), wnB = LD4(s_w2n + k * 32 + f0 + 4);
            float4 wrA = LD4(s_w2r + k * 32 + f0), wrB = LD4(s_w2r + k * 32 + f0 + 4);
            accA.x += zn * wnA.x + zr * wrA.x;
            accA.y += zn * wnA.y + zr * wrA.y;
            accA.z += zn * wnA.z + zr * wrA.z;
            accA.w += zn * wnA.w + zr * wrA.w;
            accB.x += zn * wnB.x + zr * wrB.x;
            accB.y += zn * wnB.y + zr * wrB.y;
            accB.z += zn * wnB.z + zr * wrB.z;
            accB.w += zn * wnB.w + zr * wrB.w;
        }
        h2r[0] = fmaxf(accA.x, 0.f); h2r[1] = fmaxf(accA.y, 0.f);
        h2r[2] = fmaxf(accA.z, 0.f); h2r[3] = fmaxf(accA.w, 0.f);
        h2r[4] = fmaxf(accB.x, 0.f); h2r[5] = fmaxf(accB.y, 0.f);
        h2r[6] = fmaxf(accB.z, 0.f); h2r[7] = fmaxf(accB.w, 0.f);
    }

    // ---- h3 = relu(h2@fw1 + fb1): j-slice 16 (j0 = q*16), fp16 weights ----
    float h3r[16];
    {
        const int j0 = q * 16;
        float4 a0 = LD4(s_fb1 + j0 + 0), a1 = LD4(s_fb1 + j0 + 4);
        float4 a2 = LD4(s_fb1 + j0 + 8), a3 = LD4(s_fb1 + j0 + 12);
#pragma unroll
        for (int k = 0; k < 32; ++k) {
            float hk = __shfl(h2r[k & 7], qbase + (k >> 3));
            const uint4* wp = (const uint4*)(s_fw1u + k * 32 + q * 8);
            uint4 u0 = wp[0], u1 = wp[1];
            float2 f;
            f = up2(u0.x); a0.x += hk * f.x; a0.y += hk * f.y;
            f = up2(u0.y); a0.z += hk * f.x; a0.w += hk * f.y;
            f = up2(u0.z); a1.x += hk * f.x; a1.y += hk * f.y;
            f = up2(u0.w); a1.z += hk * f.x; a1.w += hk * f.y;
            f = up2(u1.x); a2.x += hk * f.x; a2.y += hk * f.y;
            f = up2(u1.y); a2.z += hk * f.x; a2.w += hk * f.y;
            f = up2(u1.z); a3.x += hk * f.x; a3.y += hk * f.y;
            f = up2(u1.w); a3.z += hk * f.x; a3.w += hk * f.y;
        }
        h3r[0]  = fmaxf(a0.x, 0.f); h3r[1]  = fmaxf(a0.y, 0.f);
        h3r[2]  = fmaxf(a0.z, 0.f); h3r[3]  = fmaxf(a0.w, 0.f);
        h3r[4]  = fmaxf(a1.x, 0.f); h3r[5]  = fmaxf(a1.y, 0.f);
        h3r[6]  = fmaxf(a1.z, 0.f); h3r[7]  = fmaxf(a1.w, 0.f);
        h3r[8]  = fmaxf(a2.x, 0.f); h3r[9]  = fmaxf(a2.y, 0.f);
        h3r[10] = fmaxf(a2.z, 0.f); h3r[11] = fmaxf(a2.w, 0.f);
        h3r[12] = fmaxf(a3.x, 0.f); h3r[13] = fmaxf(a3.y, 0.f);
        h3r[14] = fmaxf(a3.z, 0.f); h3r[15] = fmaxf(a3.w, 0.f);
    }

    // ---- h4 = relu(h3@fw2 + fb2), out = h4@fw3 + fb3: j-slice 32, fp16 w ----
    {
        const int j0 = q * 32;
        float4 b0 = LD4(s_fb2 + j0 + 0),  b1v = LD4(s_fb2 + j0 + 4);
        float4 b2v = LD4(s_fb2 + j0 + 8), b3v = LD4(s_fb2 + j0 + 12);
        float4 b4v = LD4(s_fb2 + j0 + 16), b5v = LD4(s_fb2 + j0 + 20);
        float4 b6v = LD4(s_fb2 + j0 + 24), b7v = LD4(s_fb2 + j0 + 28);
        const unsigned int* wb = s_fw2u + q * 1032;
#pragma unroll
        for (int k = 0; k < 64; ++k) {
            float hk = __shfl(h3r[k & 15], qbase + (k >> 4));
            const uint4* wp = (const uint4*)(wb + k * 16);
            uint4 u0 = wp[0], u1 = wp[1], u2 = wp[2], u3 = wp[3];
            float2 f;
            f = up2(u0.x); b0.x  += hk * f.x; b0.y  += hk * f.y;
            f = up2(u0.y); b0.z  += hk * f.x; b0.w  += hk * f.y;
            f = up2(u0.z); b1v.x += hk * f.x; b1v.y += hk * f.y;
            f = up2(u0.w); b1v.z += hk * f.x; b1v.w += hk * f.y;
            f = up2(u1.x); b2v.x += hk * f.x; b2v.y += hk * f.y;
            f = up2(u1.y); b2v.z += hk * f.x; b2v.w += hk * f.y;
            f = up2(u1.z); b3v.x += hk * f.x; b3v.y += hk * f.y;
            f = up2(u1.w); b3v.z += hk * f.x; b3v.w += hk * f.y;
            f = up2(u2.x); b4v.x += hk * f.x; b4v.y += hk * f.y;
            f = up2(u2.y); b4v.z += hk * f.x; b4v.w += hk * f.y;
            f = up2(u2.z); b5v.x += hk * f.x; b5v.y += hk * f.y;
            f = up2(u2.w); b5v.z += hk * f.x; b5v.w += hk * f.y;
            f = up2(u3.x); b6v.x += hk * f.x; b6v.y += hk * f.y;
            f = up2(u3.y); b6v.z += hk * f.x; b6v.w += hk * f.y;
            f = up2(u3.z); b7v.x += hk * f.x; b7v.y += hk * f.y;
            f = up2(u3.w); b7v.z += hk * f.x; b7v.w += hk * f.y;
        }
        float o0 = 0.f, o1 = 0.f;
        float4 f1, f2;
#define OUTSTEP(bb, boff)                                                    \
        f1 = LD4(s_fw3 + (j0 + boff) * 2);                                   \
        f2 = LD4(s_fw3 + (j0 + boff) * 2 + 4);                               \
        { float r0 = fmaxf(bb.x, 0.f), r1 = fmaxf(bb.y, 0.f),                \
                r2 = fmaxf(bb.z, 0.f), r3 = fmaxf(bb.w, 0.f);                \
          o0 += r0 * f1.x + r1 * f1.z + r2 * f2.x + r3 * f2.z;               \
          o1 += r0 * f1.y + r1 * f1.w + r2 * f2.y + r3 * f2.w; }
        OUTSTEP(b0, 0)   OUTSTEP(b1v, 4)  OUTSTEP(b2v, 8)   OUTSTEP(b3v, 12)
        OUTSTEP(b4v, 16) OUTSTEP(b5v, 20) OUTSTEP(b6v, 24)  OUTSTEP(b7v, 28)
#undef OUTSTEP
        o0 += __shfl_xor(o0, 1); o0 += __shfl_xor(o0, 2);
        o1 += __shfl_xor(o1, 1); o1 += __shfl_xor(o1, 2);
        if (q == 0 && node < N_NODES) {
            float2 r; r.x = o0 + s_fb3[0]; r.y = o1 + s_fb3[1];
            *(float2*)(out + node * 2) = r;
        }
    }
}

extern "C" void kernel_launch(void* const* d_in, const int* in_sizes, int n_in,
                              void* d_out, int out_size, void* d_ws, size_t ws_size,
                              hipStream_t stream) {
    const float* x   = (const float*)d_in[0];
    const int*   ei  = (const int*)d_in[1];
    const int*   src = ei;
    const int*   dst = ei + N_EDGES;
    const float* w1n = (const float*)d_in[2];
    const float* w1r = (const float*)d_in[3];
    const float* b1  = (const float*)d_in[4];
    const float* w2n = (const float*)d_in[5];
    const float* w2r = (const float*)d_in[6];
    const float* b2  = (const float*)d_in[7];
    const float* fw1 = (const float*)d_in[8];
    const float* fb1 = (const float*)d_in[9];
    const float* fw2 = (const float*)d_in[10];
    const float* fb2 = (const float*)d_in[11];
    const float* fw3 = (const float*)d_in[12];
    const float* fb3 = (const float*)d_in[13];
    float* out = (float*)d_out;

    // workspace layout (~18 MB)
    unsigned int*   nbrU        = (unsigned int*)d_ws;              // 50000*32 uints (6.4MB)
    int*            deg         = (int*)(nbrU + N_NODES * 32);      // 50000
    __half*         xw1n        = (__half*)(deg + N_NODES);         // 800000
    __half*         xr1b        = xw1n + N_EDGES;                   // 800000
    __half*         h1          = xr1b + N_EDGES;                   // 800000
    __half*         agg2        = h1 + N_EDGES;                     // 800000
    unsigned int*   staging     = (unsigned int*)(agg2 + N_EDGES);  // 800000 (3.2MB)
    int*            ghist       = (int*)(staging + N_EDGES);        // 100096
    int*            gscan       = ghist + NENT;                     // 100096
    int*            bucketStart = gscan + NENT;                     // 392

    const unsigned short* nbr = (const unsigned short*)nbrU;

    k_lin1<<<N_EDGES / 256, 256, 0, stream>>>(x, w1n, w1r, b1, xw1n, xr1b);
    k_hist<<<NSCB, 256, 0, stream>>>(dst, ghist);
    k_scan<<<1, 256, 0, stream>>>(ghist, gscan, bucketStart);
    k_scatter<<<NSCB, 256, 0, stream>>>(src, dst, gscan, staging);
    k_build<<<NBUCKET, 256, 0, stream>>>(staging, bucketStart, nbrU, deg);
    k_agg1<<<(N_NODES * 16 + 255) / 256, 256, 0, stream>>>(xw1n, xr1b, deg, nbr, h1);
    k_agg2<<<(N_NODES * 16 + 255) / 256, 256, 0, stream>>>(h1, deg, nbr, agg2);
    k_head<<<(N_NODES + 63) / 64, 256, 0, stream>>>(h1, agg2, w2n, w2r, b2,
                                                    fw1, fb1, fw2, fb2, fw3, fb3, out);
}

// Round 8
// 108.635 us; speedup vs baseline: 2.3786x; 2.3786x over previous
//
#include <hip/hip_runtime.h>
#include <hip/hip_fp16.h>

#define N_NODES 50000
#define N_EDGES 800000
#define D_IN 64
#define MAXD 64
#define BSHIFT 7                       // 128 nodes per bucket
#define BNODES 128
#define NBUCKET 391                    // ceil(50000/128)
#define NSCB 128                       // hist/scatter blocks
#define EPB (N_EDGES / NSCB)           // 6250 edges per block
#define NENT (NBUCKET * NSCB)          // 50048 (bucket-major)
#define SCB ((NENT + 255) / 256)       // 196 scan blocks
#define LD4(p) (*(const float4*)(p))

__device__ __forceinline__ float2 up2(unsigned int u) {
    return __half22float2(*(__half2*)&u);
}
__device__ __forceinline__ unsigned int pk2(float lo, float hi) {
    __half2 h = __floats2half2_rn(lo, hi);
    return *(unsigned int*)&h;
}

// ---- K0: node linears: xw1n = x@w1n ; xr1b = x@w1r + b1 (fp16 out) ----
__global__ __launch_bounds__(256) void k_lin1(
        const float* __restrict__ x,
        const float* __restrict__ w1n, const float* __restrict__ w1r,
        const float* __restrict__ b1,
        __half* __restrict__ xw1n, __half* __restrict__ xr1b) {
    __shared__ float wn[1024], wr[1024], bs[16];
    for (int i = threadIdx.x; i < 1024; i += 256) { wn[i] = w1n[i]; wr[i] = w1r[i]; }
    if (threadIdx.x < 16) bs[threadIdx.x] = b1[threadIdx.x];
    __syncthreads();
    const int t = blockIdx.x * 256 + threadIdx.x;   // 800000 threads exactly
    const int node = t >> 4, f = t & 15;
    const float* xr = x + node * D_IN;
    float an = 0.f, ar = bs[f];
#pragma unroll
    for (int k = 0; k < D_IN; ++k) {
        float xv = xr[k];
        an += xv * wn[k * 16 + f];
        ar += xv * wr[k * 16 + f];
    }
    xw1n[t] = __float2half(an);
    xr1b[t] = __float2half(ar);
}

// ---- K1: per-block bucket histogram (bucket-major output) ----
__global__ __launch_bounds__(256) void k_hist(const int* __restrict__ dst,
                                              int* __restrict__ ghist) {
    __shared__ int lh[NBUCKET];
    for (int i = threadIdx.x; i < NBUCKET; i += 256) lh[i] = 0;
    __syncthreads();
    const int base = blockIdx.x * EPB;
    for (int i = threadIdx.x; i < EPB; i += 256)
        atomicAdd(&lh[dst[base + i] >> BSHIFT], 1);
    __syncthreads();
    for (int i = threadIdx.x; i < NBUCKET; i += 256)
        ghist[i * NSCB + blockIdx.x] = lh[i];
}

// ---- K2a: per-block exclusive scan + block sums ----
__global__ __launch_bounds__(256) void k_scanA(const int* __restrict__ ghist,
                                               int* __restrict__ part,
                                               int* __restrict__ blockSums) {
    __shared__ int s[256];
    const int i = blockIdx.x * 256 + threadIdx.x;
    int v = (i < NENT) ? ghist[i] : 0;
    s[threadIdx.x] = v;
    __syncthreads();
    for (int d = 1; d < 256; d <<= 1) {
        int t = (threadIdx.x >= d) ? s[threadIdx.x - d] : 0;
        __syncthreads();
        s[threadIdx.x] += t;
        __syncthreads();
    }
    if (i < NENT) part[i] = s[threadIdx.x] - v;      // exclusive within block
    if (threadIdx.x == 255) blockSums[blockIdx.x] = s[255];
}

// ---- K2b: scan of SCB block sums (one tiny block) ----
__global__ __launch_bounds__(256) void k_scanB(int* __restrict__ blockSums) {
    __shared__ int s[256];
    const int t = threadIdx.x;
    int v = (t < SCB) ? blockSums[t] : 0;
    s[t] = v;
    __syncthreads();
    for (int d = 1; d < 256; d <<= 1) {
        int u = (t >= d) ? s[t - d] : 0;
        __syncthreads();
        s[t] += u;
        __syncthreads();
    }
    if (t < SCB) blockSums[t] = s[t] - v;            // exclusive
}

// ---- K2c: add-back + bucketStart extraction ----
__global__ __launch_bounds__(256) void k_scanC(const int* __restrict__ part,
                                               const int* __restrict__ blockSums,
                                               int* __restrict__ gscan,
                                               int* __restrict__ bucketStart) {
    const int i = blockIdx.x * 256 + threadIdx.x;
    if (i < NENT) {
        int o = part[i] + blockSums[blockIdx.x];
        gscan[i] = o;
        if ((i & (NSCB - 1)) == 0) bucketStart[i >> BSHIFT] = o;
    }
    if (i == 0) bucketStart[NBUCKET] = N_EDGES;
}

// ---- K3: scatter edges into bucket-grouped staging (packed u32) ----
__global__ __launch_bounds__(256) void k_scatter(const int* __restrict__ src,
                                                 const int* __restrict__ dst,
                                                 const int* __restrict__ gscan,
                                                 unsigned int* __restrict__ staging) {
    __shared__ int cur[NBUCKET];
    for (int i = threadIdx.x; i < NBUCKET; i += 256)
        cur[i] = gscan[i * NSCB + blockIdx.x];
    __syncthreads();
    const int base = blockIdx.x * EPB;
    for (int i = threadIdx.x; i < EPB; i += 256) {
        int d = dst[base + i], s = src[base + i];
        int pos = atomicAdd(&cur[d >> BSHIFT], 1);
        staging[pos] = ((unsigned int)(d & (BNODES - 1)) << 16) | (unsigned int)s;
    }
}

// ---- K4: per-bucket padded-table build in LDS, coalesced write-out ----
__global__ __launch_bounds__(256) void k_build(const unsigned int* __restrict__ staging,
                                               const int* __restrict__ bucketStart,
                                               unsigned int* __restrict__ nbrU,
                                               int* __restrict__ deg) {
    __shared__ unsigned short ltbl[BNODES * MAXD];
    __shared__ int lcnt[BNODES];
    const int tid = threadIdx.x, b = blockIdx.x;
    if (tid < BNODES) lcnt[tid] = 0;
    __syncthreads();
    const int beg = bucketStart[b], end = bucketStart[b + 1];
    for (int i = beg + tid; i < end; i += 256) {
        unsigned int u = staging[i];
        int dl = u >> 16, s = u & 0xFFFF;
        int slot = atomicAdd(&lcnt[dl], 1);
        if (slot < MAXD) ltbl[(dl << 6) + slot] = (unsigned short)s;
    }
    __syncthreads();
    const int nbase = b << BSHIFT;
    for (int i = tid; i < BNODES * 32; i += 256) {
        int nl = i >> 5, j = i & 31;
        int node = nbase + nl;
        if (node < N_NODES && 2 * j < lcnt[nl]) {
            unsigned int lo = ltbl[(nl << 6) + 2 * j];
            unsigned int hi = ltbl[(nl << 6) + 2 * j + 1];
            nbrU[(node << 5) + j] = lo | (hi << 16);
        }
    }
    if (tid < BNODES && nbase + tid < N_NODES) deg[nbase + tid] = lcnt[tid];
}

// ---- K5: h1 = relu(mean_nbrs(xw1n) + xr1b) ----
__global__ __launch_bounds__(256) void k_agg1(
        const __half* __restrict__ xw1n, const __half* __restrict__ xr1b,
        const int* __restrict__ deg, const unsigned short* __restrict__ nbr,
        __half* __restrict__ h1) {
    const int t = blockIdx.x * 256 + threadIdx.x;
    if (t >= N_NODES * 16) return;
    const int node = t >> 4, f = t & 15;
    int c = deg[node];
    float inv = c > 0 ? 1.f / (float)c : 1.f;
    int cc = c > MAXD ? MAXD : c;
    const unsigned short* np = nbr + (node << 6);
    float a0 = 0.f, a1 = 0.f, a2 = 0.f, a3 = 0.f;
    int j = 0;
    for (; j + 4 <= cc; j += 4) {
        int s0 = np[j], s1 = np[j + 1], s2 = np[j + 2], s3 = np[j + 3];
        a0 += __half2float(xw1n[(s0 << 4) + f]);
        a1 += __half2float(xw1n[(s1 << 4) + f]);
        a2 += __half2float(xw1n[(s2 << 4) + f]);
        a3 += __half2float(xw1n[(s3 << 4) + f]);
    }
    for (; j < cc; ++j) a0 += __half2float(xw1n[(np[j] << 4) + f]);
    h1[t] = __float2half(fmaxf((a0 + a1 + a2 + a3) * inv + __half2float(xr1b[t]), 0.f));
}

// ---- K6: agg2 = mean_nbrs(h1)  (fp16 out) ----
__global__ __launch_bounds__(256) void k_agg2(
        const __half* __restrict__ h1,
        const int* __restrict__ deg, const unsigned short* __restrict__ nbr,
        __half* __restrict__ agg2) {
    const int t = blockIdx.x * 256 + threadIdx.x;
    if (t >= N_NODES * 16) return;
    const int node = t >> 4, f = t & 15;
    int c = deg[node];
    float inv = c > 0 ? 1.f / (float)c : 1.f;
    int cc = c > MAXD ? MAXD : c;
    const unsigned short* np = nbr + (node << 6);
    float a0 = 0.f, a1 = 0.f, a2 = 0.f, a3 = 0.f;
    int j = 0;
    for (; j + 4 <= cc; j += 4) {
        int s0 = np[j], s1 = np[j + 1], s2 = np[j + 2], s3 = np[j + 3];
        a0 += __half2float(h1[(s0 << 4) + f]);
        a1 += __half2float(h1[(s1 << 4) + f]);
        a2 += __half2float(h1[(s2 << 4) + f]);
        a3 += __half2float(h1[(s3 << 4) + f]);
    }
    for (; j < cc; ++j) a0 += __half2float(h1[(np[j] << 4) + f]);
    agg2[t] = __float2half((a0 + a1 + a2 + a3) * inv);
}

// ---- K7 (k_head): pure dense SAGE2 + MLP head; fp16-packed fw1/fw2 ----
__global__ __launch_bounds__(256) void k_head(
        const __half* __restrict__ h1, const __half* __restrict__ agg2,
        const float* __restrict__ w2n, const float* __restrict__ w2r,
        const float* __restrict__ b2,
        const float* __restrict__ fw1, const float* __restrict__ fb1,
        const float* __restrict__ fw2, const float* __restrict__ fb2,
        const float* __restrict__ fw3, const float* __restrict__ fb3,
        float* __restrict__ out) {
    __shared__ __align__(16) float s_w2n[512];
    __shared__ __align__(16) float s_w2r[512];
    __shared__ __align__(16) unsigned int s_fw1u[1024];      // [k][32 half2]
    __shared__ __align__(16) unsigned int s_fw2u[4 * 1032];  // [q][k][16 half2]+pad8
    __shared__ __align__(16) float s_fw3[256];
    __shared__ __align__(16) float s_b2[32];
    __shared__ __align__(16) float s_fb1[64];
    __shared__ __align__(16) float s_fb2[128];
    __shared__ float s_fb3[2];

    const int tid = threadIdx.x;
    for (int i = tid; i < 512; i += 256) { s_w2n[i] = w2n[i]; s_w2r[i] = w2r[i]; }
    for (int i = tid; i < 1024; i += 256) {                  // fw1 [32x64] -> half2
        int k = i >> 5, p = i & 31;
        s_fw1u[k * 32 + p] = pk2(fw1[k * 64 + 2 * p], fw1[k * 64 + 2 * p + 1]);
    }
    for (int i = tid; i < 4096; i += 256) {                  // fw2 [64x128] -> half2
        int k = i >> 6, p = i & 63;
        s_fw2u[(p >> 4) * 1032 + k * 16 + (p & 15)] =
            pk2(fw2[k * 128 + 2 * p], fw2[k * 128 + 2 * p + 1]);
    }
    s_fw3[tid] = fw3[tid & 255];
    if (tid < 32) s_b2[tid] = b2[tid];
    if (tid < 64) s_fb1[tid] = fb1[tid];
    if (tid < 128) s_fb2[tid] = fb2[tid];
    if (tid < 2) s_fb3[tid] = fb3[tid];
    __syncthreads();

    const int nl = tid >> 2;             // node local 0..63
    const int q  = tid & 3;              // quarter lane
    const int node = blockIdx.x * 64 + nl;
    const int nodec = node < N_NODES ? node : (N_NODES - 1);
    const int qbase = (tid & 63) & ~3;   // quad base lane in wave

    float za[4], zh[4];
    {
        const __half2* ap = (const __half2*)(agg2 + (nodec << 4) + (q << 2));
        const __half2* hp = (const __half2*)(h1 + (nodec << 4) + (q << 2));
        float2 v0 = __half22float2(ap[0]), v1 = __half22float2(ap[1]);
        za[0] = v0.x; za[1] = v0.y; za[2] = v1.x; za[3] = v1.y;
        float2 w0 = __half22float2(hp[0]), w1 = __half22float2(hp[1]);
        zh[0] = w0.x; zh[1] = w0.y; zh[2] = w1.x; zh[3] = w1.y;
    }

    // ---- h2 = relu(agg@w2n + h1@w2r + b2): f-slice 8 (f0 = q*8) ----
    float h2r[8];
    {
        const int f0 = q * 8;
        float4 accA = LD4(s_b2 + f0), accB = LD4(s_b2 + f0 + 4);
#pragma unroll
        for (int k = 0; k < 16; ++k) {
            int sl = qbase + (k >> 2);
            float zn = __shfl(za[k & 3], sl);
            float zr = __shfl(zh[k & 3], sl);
            float4 wnA = LD4(s_w2n + k * 32 + f0), wnB = LD4(s_w2n + k * 32 + f0 + 4);
            float4 wrA = LD4(s_w2r + k * 32 + f0), wrB = LD4(s_w2r + k * 32 + f0 + 4);
            accA.x += zn * wnA.x + zr * wrA.x;
            accA.y += zn * wnA.y + zr * wrA.y;
            accA.z += zn * wnA.z + zr * wrA.z;
            accA.w += zn * wnA.w + zr * wrA.w;
            accB.x += zn * wnB.x + zr * wrB.x;
            accB.y += zn * wnB.y + zr * wrB.y;
            accB.z += zn * wnB.z + zr * wrB.z;
            accB.w += zn * wnB.w + zr * wrB.w;
        }
        h2r[0] = fmaxf(accA.x, 0.f); h2r[1] = fmaxf(accA.y, 0.f);
        h2r[2] = fmaxf(accA.z, 0.f); h2r[3] = fmaxf(accA.w, 0.f);
        h2r[4] = fmaxf(accB.x, 0.f); h2r[5] = fmaxf(accB.y, 0.f);
        h2r[6] = fmaxf(accB.z, 0.f); h2r[7] = fmaxf(accB.w, 0.f);
    }

    // ---- h3 = relu(h2@fw1 + fb1): j-slice 16 (j0 = q*16), fp16 weights ----
    float h3r[16];
    {
        const int j0 = q * 16;
        float4 a0 = LD4(s_fb1 + j0 + 0), a1 = LD4(s_fb1 + j0 + 4);
        float4 a2 = LD4(s_fb1 + j0 + 8), a3 = LD4(s_fb1 + j0 + 12);
#pragma unroll
        for (int k = 0; k < 32; ++k) {
            float hk = __shfl(h2r[k & 7], qbase + (k >> 3));
            const uint4* wp = (const uint4*)(s_fw1u + k * 32 + q * 8);
            uint4 u0 = wp[0], u1 = wp[1];
            float2 f;
            f = up2(u0.x); a0.x += hk * f.x; a0.y += hk * f.y;
            f = up2(u0.y); a0.z += hk * f.x; a0.w += hk * f.y;
            f = up2(u0.z); a1.x += hk * f.x; a1.y += hk * f.y;
            f = up2(u0.w); a1.z += hk * f.x; a1.w += hk * f.y;
            f = up2(u1.x); a2.x += hk * f.x; a2.y += hk * f.y;
            f = up2(u1.y); a2.z += hk * f.x; a2.w += hk * f.y;
            f = up2(u1.z); a3.x += hk * f.x; a3.y += hk * f.y;
            f = up2(u1.w); a3.z += hk * f.x; a3.w += hk * f.y;
        }
        h3r[0]  = fmaxf(a0.x, 0.f); h3r[1]  = fmaxf(a0.y, 0.f);
        h3r[2]  = fmaxf(a0.z, 0.f); h3r[3]  = fmaxf(a0.w, 0.f);
        h3r[4]  = fmaxf(a1.x, 0.f); h3r[5]  = fmaxf(a1.y, 0.f);
        h3r[6]  = fmaxf(a1.z, 0.f); h3r[7]  = fmaxf(a1.w, 0.f);
        h3r[8]  = fmaxf(a2.x, 0.f); h3r[9]  = fmaxf(a2.y, 0.f);
        h3r[10] = fmaxf(a2.z, 0.f); h3r[11] = fmaxf(a2.w, 0.f);
        h3r[12] = fmaxf(a3.x, 0.f); h3r[13] = fmaxf(a3.y, 0.f);
        h3r[14] = fmaxf(a3.z, 0.f); h3r[15] = fmaxf(a3.w, 0.f);
    }

    // ---- h4 = relu(h3@fw2 + fb2), out = h4@fw3 + fb3: j-slice 32, fp16 w ----
    {
        const int j0 = q * 32;
        float4 b0 = LD4(s_fb2 + j0 + 0),  b1v = LD4(s_fb2 + j0 + 4);
        float4 b2v = LD4(s_fb2 + j0 + 8), b3v = LD4(s_fb2 + j0 + 12);
        float4 b4v = LD4(s_fb2 + j0 + 16), b5v = LD4(s_fb2 + j0 + 20);
        float4 b6v = LD4(s_fb2 + j0 + 24), b7v = LD4(s_fb2 + j0 + 28);
        const unsigned int* wb = s_fw2u + q * 1032;
#pragma unroll
        for (int k = 0; k < 64; ++k) {
            float hk = __shfl(h3r[k & 15], qbase + (k >> 4));
            const uint4* wp = (const uint4*)(wb + k * 16);
            uint4 u0 = wp[0], u1 = wp[1], u2 = wp[2], u3 = wp[3];
            float2 f;
            f = up2(u0.x); b0.x  += hk * f.x; b0.y  += hk * f.y;
            f = up2(u0.y); b0.z  += hk * f.x; b0.w  += hk * f.y;
            f = up2(u0.z); b1v.x += hk * f.x; b1v.y += hk * f.y;
            f = up2(u0.w); b1v.z += hk * f.x; b1v.w += hk * f.y;
            f = up2(u1.x); b2v.x += hk * f.x; b2v.y += hk * f.y;
            f = up2(u1.y); b2v.z += hk * f.x; b2v.w += hk * f.y;
            f = up2(u1.z); b3v.x += hk * f.x; b3v.y += hk * f.y;
            f = up2(u1.w); b3v.z += hk * f.x; b3v.w += hk * f.y;
            f = up2(u2.x); b4v.x += hk * f.x; b4v.y += hk * f.y;
            f = up2(u2.y); b4v.z += hk * f.x; b4v.w += hk * f.y;
            f = up2(u2.z); b5v.x += hk * f.x; b5v.y += hk * f.y;
            f = up2(u2.w); b5v.z += hk * f.x; b5v.w += hk * f.y;
            f = up2(u3.x); b6v.x += hk * f.x; b6v.y += hk * f.y;
            f = up2(u3.y); b6v.z += hk * f.x; b6v.w += hk * f.y;
            f = up2(u3.z); b7v.x += hk * f.x; b7v.y += hk * f.y;
            f = up2(u3.w); b7v.z += hk * f.x; b7v.w += hk * f.y;
        }
        float o0 = 0.f, o1 = 0.f;
        float4 f1, f2;
#define OUTSTEP(bb, boff)                                                    \
        f1 = LD4(s_fw3 + (j0 + boff) * 2);                                   \
        f2 = LD4(s_fw3 + (j0 + boff) * 2 + 4);                               \
        { float r0 = fmaxf(bb.x, 0.f), r1 = fmaxf(bb.y, 0.f),                \
                r2 = fmaxf(bb.z, 0.f), r3 = fmaxf(bb.w, 0.f);                \
          o0 += r0 * f1.x + r1 * f1.z + r2 * f2.x + r3 * f2.z;               \
          o1 += r0 * f1.y + r1 * f1.w + r2 * f2.y + r3 * f2.w; }
        OUTSTEP(b0, 0)   OUTSTEP(b1v, 4)  OUTSTEP(b2v, 8)   OUTSTEP(b3v, 12)
        OUTSTEP(b4v, 16) OUTSTEP(b5v, 20) OUTSTEP(b6v, 24)  OUTSTEP(b7v, 28)
#undef OUTSTEP
        o0 += __shfl_xor(o0, 1); o0 += __shfl_xor(o0, 2);
        o1 += __shfl_xor(o1, 1); o1 += __shfl_xor(o1, 2);
        if (q == 0 && node < N_NODES) {
            float2 r; r.x = o0 + s_fb3[0]; r.y = o1 + s_fb3[1];
            *(float2*)(out + node * 2) = r;
        }
    }
}

extern "C" void kernel_launch(void* const* d_in, const int* in_sizes, int n_in,
                              void* d_out, int out_size, void* d_ws, size_t ws_size,
                              hipStream_t stream) {
    const float* x   = (const float*)d_in[0];
    const int*   ei  = (const int*)d_in[1];
    const int*   src = ei;
    const int*   dst = ei + N_EDGES;
    const float* w1n = (const float*)d_in[2];
    const float* w1r = (const float*)d_in[3];
    const float* b1  = (const float*)d_in[4];
    const float* w2n = (const float*)d_in[5];
    const float* w2r = (const float*)d_in[6];
    const float* b2  = (const float*)d_in[7];
    const float* fw1 = (const float*)d_in[8];
    const float* fb1 = (const float*)d_in[9];
    const float* fw2 = (const float*)d_in[10];
    const float* fb2 = (const float*)d_in[11];
    const float* fw3 = (const float*)d_in[12];
    const float* fb3 = (const float*)d_in[13];
    float* out = (float*)d_out;

    // workspace layout (~18.6 MB)
    unsigned int*   nbrU        = (unsigned int*)d_ws;              // 50000*32 uints (6.4MB)
    int*            deg         = (int*)(nbrU + N_NODES * 32);      // 50000
    __half*         xw1n        = (__half*)(deg + N_NODES);         // 800000
    __half*         xr1b        = xw1n + N_EDGES;                   // 800000
    __half*         h1          = xr1b + N_EDGES;                   // 800000
    __half*         agg2        = h1 + N_EDGES;                     // 800000
    unsigned int*   staging     = (unsigned int*)(agg2 + N_EDGES);  // 800000 (3.2MB)
    int*            ghist       = (int*)(staging + N_EDGES);        // 50048
    int*            gscan       = ghist + NENT;                     // 50048
    int*            part        = gscan + NENT;                     // 50048
    int*            blockSums   = part + NENT;                      // 196
    int*            bucketStart = blockSums + SCB;                  // 392

    const unsigned short* nbr = (const unsigned short*)nbrU;

    k_lin1<<<N_EDGES / 256, 256, 0, stream>>>(x, w1n, w1r, b1, xw1n, xr1b);
    k_hist<<<NSCB, 256, 0, stream>>>(dst, ghist);
    k_scanA<<<SCB, 256, 0, stream>>>(ghist, part, blockSums);
    k_scanB<<<1, 256, 0, stream>>>(blockSums);
    k_scanC<<<SCB, 256, 0, stream>>>(part, blockSums, gscan, bucketStart);
    k_scatter<<<NSCB, 256, 0, stream>>>(src, dst, gscan, staging);
    k_build<<<NBUCKET, 256, 0, stream>>>(staging, bucketStart, nbrU, deg);
    k_agg1<<<(N_NODES * 16 + 255) / 256, 256, 0, stream>>>(xw1n, xr1b, deg, nbr, h1);
    k_agg2<<<(N_NODES * 16 + 255) / 256, 256, 0, stream>>>(h1, deg, nbr, agg2);
    k_head<<<(N_NODES + 63) / 64, 256, 0, stream>>>(h1, agg2, w2n, w2r, b2,
                                                    fw1, fb1, fw2, fb2, fw3, fb3, out);
}

// Round 9
// 72.473 us; speedup vs baseline: 3.5654x; 1.4990x over previous
//
#include <hip/hip_runtime.h>
#include <hip/hip_fp16.h>

#define N_NODES 50000
#define N_EDGES 800000
#define D_IN 64
#define MAXD 64
#define BSHIFT 7                       // 128 nodes per bucket
#define BNODES 128
#define NBUCKET 391                    // ceil(50000/128)
#define NSCB 128                       // hist/scatter blocks
#define EPB (N_EDGES / NSCB)           // 6250 edges per block
#define NENT (NBUCKET * NSCB)          // 50048 (bucket-major)
#define SCB ((NENT + 255) / 256)       // 196 scan blocks

typedef _Float16 f16x8 __attribute__((ext_vector_type(8)));
typedef float f32x4 __attribute__((ext_vector_type(4)));

union H8 { uint4 v; unsigned int u[4]; f16x8 h; };

__device__ __forceinline__ f32x4 MM(const H8& a, const H8& b, f32x4 c) {
    return __builtin_amdgcn_mfma_f32_16x16x32_f16(a.h, b.h, c, 0, 0, 0);
}
__device__ __forceinline__ unsigned int pkh(float a, float b) {
    __half2 h = __floats2half2_rn(a, b);
    unsigned int u;
    __builtin_memcpy(&u, &h, 4);
    return u;
}

// ---- K0 (MFMA): xw1n = x@w1n ; xr1b = x@w1r + b1 (fp16 out) ----
// wave = 16 nodes. D[out][node] = W^T A-op (LDS f16) x^T B-op (global f32->f16).
__global__ __launch_bounds__(256) void k_lin1(
        const float* __restrict__ x,
        const float* __restrict__ w1n, const float* __restrict__ w1r,
        const float* __restrict__ b1,
        __half* __restrict__ xw1n, __half* __restrict__ xr1b) {
    __shared__ __align__(16) __half s_w1t[32 * 72];   // [out 32][k 64 pad 72]
    const int tid = threadIdx.x;
    for (int i = tid; i < 2048; i += 256) {
        int o = i & 31, k = i >> 5;
        float v = (o < 16) ? w1n[k * 16 + o] : w1r[k * 16 + (o - 16)];
        s_w1t[o * 72 + k] = __float2half(v);
    }
    __syncthreads();
    const int l = tid & 63, li = l & 15, g = l >> 4;
    const int wid = tid >> 6;
    const int node = blockIdx.x * 64 + wid * 16 + li;
    const int nodec = node < N_NODES ? node : N_NODES - 1;

    // B frags: x[node][k], k = 8g..+8 (s=0) and 32+8g..+8 (s=1)
    H8 B0, B1;
    {
        const float4* xp = (const float4*)(x + nodec * 64 + 8 * g);
        float4 v0 = xp[0], v1 = xp[1];
        B0.u[0] = pkh(v0.x, v0.y); B0.u[1] = pkh(v0.z, v0.w);
        B0.u[2] = pkh(v1.x, v1.y); B0.u[3] = pkh(v1.z, v1.w);
        const float4* xq = (const float4*)(x + nodec * 64 + 32 + 8 * g);
        float4 w0 = xq[0], w1 = xq[1];
        B1.u[0] = pkh(w0.x, w0.y); B1.u[1] = pkh(w0.z, w0.w);
        B1.u[2] = pkh(w1.x, w1.y); B1.u[3] = pkh(w1.z, w1.w);
    }
    H8 A;
    f32x4 c0 = {0.f, 0.f, 0.f, 0.f};                       // t=0 -> xw1n
    A.v = *(const uint4*)(s_w1t + li * 72 + 8 * g);
    c0 = MM(A, B0, c0);
    A.v = *(const uint4*)(s_w1t + li * 72 + 32 + 8 * g);
    c0 = MM(A, B1, c0);
    f32x4 c1 = *(const f32x4*)(b1 + 4 * g);                // t=1 -> xr1b (+b1)
    A.v = *(const uint4*)(s_w1t + (16 + li) * 72 + 8 * g);
    c1 = MM(A, B0, c1);
    A.v = *(const uint4*)(s_w1t + (16 + li) * 72 + 32 + 8 * g);
    c1 = MM(A, B1, c1);

    if (node < N_NODES) {
        uint2 s0, s1;
        s0.x = pkh(c0[0], c0[1]); s0.y = pkh(c0[2], c0[3]);
        s1.x = pkh(c1[0], c1[1]); s1.y = pkh(c1[2], c1[3]);
        *(uint2*)(xw1n + node * 16 + 4 * g) = s0;          // feats 4g..4g+3
        *(uint2*)(xr1b + node * 16 + 4 * g) = s1;
    }
}

// ---- K1: per-block bucket histogram (bucket-major output) ----
__global__ __launch_bounds__(256) void k_hist(const int* __restrict__ dst,
                                              int* __restrict__ ghist) {
    __shared__ int lh[NBUCKET];
    for (int i = threadIdx.x; i < NBUCKET; i += 256) lh[i] = 0;
    __syncthreads();
    const int base = blockIdx.x * EPB;
    for (int i = threadIdx.x; i < EPB; i += 256)
        atomicAdd(&lh[dst[base + i] >> BSHIFT], 1);
    __syncthreads();
    for (int i = threadIdx.x; i < NBUCKET; i += 256)
        ghist[i * NSCB + blockIdx.x] = lh[i];
}

// ---- K2a: per-block exclusive scan + block sums ----
__global__ __launch_bounds__(256) void k_scanA(const int* __restrict__ ghist,
                                               int* __restrict__ part,
                                               int* __restrict__ blockSums) {
    __shared__ int s[256];
    const int i = blockIdx.x * 256 + threadIdx.x;
    int v = (i < NENT) ? ghist[i] : 0;
    s[threadIdx.x] = v;
    __syncthreads();
    for (int d = 1; d < 256; d <<= 1) {
        int t = (threadIdx.x >= d) ? s[threadIdx.x - d] : 0;
        __syncthreads();
        s[threadIdx.x] += t;
        __syncthreads();
    }
    if (i < NENT) part[i] = s[threadIdx.x] - v;
    if (threadIdx.x == 255) blockSums[blockIdx.x] = s[255];
}

// ---- K2b: scan of SCB block sums ----
__global__ __launch_bounds__(256) void k_scanB(int* __restrict__ blockSums) {
    __shared__ int s[256];
    const int t = threadIdx.x;
    int v = (t < SCB) ? blockSums[t] : 0;
    s[t] = v;
    __syncthreads();
    for (int d = 1; d < 256; d <<= 1) {
        int u = (t >= d) ? s[t - d] : 0;
        __syncthreads();
        s[t] += u;
        __syncthreads();
    }
    if (t < SCB) blockSums[t] = s[t] - v;
}

// ---- K2c: add-back + bucketStart extraction ----
__global__ __launch_bounds__(256) void k_scanC(const int* __restrict__ part,
                                               const int* __restrict__ blockSums,
                                               int* __restrict__ gscan,
                                               int* __restrict__ bucketStart) {
    const int i = blockIdx.x * 256 + threadIdx.x;
    if (i < NENT) {
        int o = part[i] + blockSums[blockIdx.x];
        gscan[i] = o;
        if ((i & (NSCB - 1)) == 0) bucketStart[i >> BSHIFT] = o;
    }
    if (i == 0) bucketStart[NBUCKET] = N_EDGES;
}

// ---- K3: scatter edges into bucket-grouped staging (packed u32) ----
__global__ __launch_bounds__(256) void k_scatter(const int* __restrict__ src,
                                                 const int* __restrict__ dst,
                                                 const int* __restrict__ gscan,
                                                 unsigned int* __restrict__ staging) {
    __shared__ int cur[NBUCKET];
    for (int i = threadIdx.x; i < NBUCKET; i += 256)
        cur[i] = gscan[i * NSCB + blockIdx.x];
    __syncthreads();
    const int base = blockIdx.x * EPB;
    for (int i = threadIdx.x; i < EPB; i += 256) {
        int d = dst[base + i], s = src[base + i];
        int pos = atomicAdd(&cur[d >> BSHIFT], 1);
        staging[pos] = ((unsigned int)(d & (BNODES - 1)) << 16) | (unsigned int)s;
    }
}

// ---- K4: per-bucket padded-table build in LDS, coalesced write-out ----
__global__ __launch_bounds__(256) void k_build(const unsigned int* __restrict__ staging,
                                               const int* __restrict__ bucketStart,
                                               unsigned int* __restrict__ nbrU,
                                               int* __restrict__ deg) {
    __shared__ unsigned short ltbl[BNODES * MAXD];
    __shared__ int lcnt[BNODES];
    const int tid = threadIdx.x, b = blockIdx.x;
    if (tid < BNODES) lcnt[tid] = 0;
    __syncthreads();
    const int beg = bucketStart[b], end = bucketStart[b + 1];
    for (int i = beg + tid; i < end; i += 256) {
        unsigned int u = staging[i];
        int dl = u >> 16, s = u & 0xFFFF;
        int slot = atomicAdd(&lcnt[dl], 1);
        if (slot < MAXD) ltbl[(dl << 6) + slot] = (unsigned short)s;
    }
    __syncthreads();
    const int nbase = b << BSHIFT;
    for (int i = tid; i < BNODES * 32; i += 256) {
        int nl = i >> 5, j = i & 31;
        int node = nbase + nl;
        if (node < N_NODES && 2 * j < lcnt[nl]) {
            unsigned int lo = ltbl[(nl << 6) + 2 * j];
            unsigned int hi = ltbl[(nl << 6) + 2 * j + 1];
            nbrU[(node << 5) + j] = lo | (hi << 16);
        }
    }
    if (tid < BNODES && nbase + tid < N_NODES) deg[nbase + tid] = lcnt[tid];
}

// ---- K5: h1 = relu(mean_nbrs(xw1n) + xr1b)  (half2 lanes: 8 thr/node) ----
__global__ __launch_bounds__(256) void k_agg1(
        const __half* __restrict__ xw1n, const __half* __restrict__ xr1b,
        const int* __restrict__ deg, const unsigned short* __restrict__ nbr,
        __half* __restrict__ h1) {
    const int t = blockIdx.x * 256 + threadIdx.x;
    if (t >= N_NODES * 8) return;
    const int node = t >> 3, fp = t & 7;
    int c = deg[node];
    float inv = c > 0 ? 1.f / (float)c : 1.f;
    int cc = c > MAXD ? MAXD : c;
    const unsigned short* np = nbr + (node << 6);
    float2 a0 = {0.f, 0.f}, a1 = {0.f, 0.f}, a2 = {0.f, 0.f}, a3 = {0.f, 0.f};
    int j = 0;
    for (; j + 4 <= cc; j += 4) {
        float2 v0 = __half22float2(*(const __half2*)(xw1n + (np[j + 0] << 4) + (fp << 1)));
        float2 v1 = __half22float2(*(const __half2*)(xw1n + (np[j + 1] << 4) + (fp << 1)));
        float2 v2 = __half22float2(*(const __half2*)(xw1n + (np[j + 2] << 4) + (fp << 1)));
        float2 v3 = __half22float2(*(const __half2*)(xw1n + (np[j + 3] << 4) + (fp << 1)));
        a0.x += v0.x; a0.y += v0.y; a1.x += v1.x; a1.y += v1.y;
        a2.x += v2.x; a2.y += v2.y; a3.x += v3.x; a3.y += v3.y;
    }
    for (; j < cc; ++j) {
        float2 v = __half22float2(*(const __half2*)(xw1n + (np[j] << 4) + (fp << 1)));
        a0.x += v.x; a0.y += v.y;
    }
    float2 r = __half22float2(*(const __half2*)(xr1b + (node << 4) + (fp << 1)));
    float rx = fmaxf((a0.x + a1.x + a2.x + a3.x) * inv + r.x, 0.f);
    float ry = fmaxf((a0.y + a1.y + a2.y + a3.y) * inv + r.y, 0.f);
    *(__half2*)(h1 + (node << 4) + (fp << 1)) = __floats2half2_rn(rx, ry);
}

// ---- K6: agg2 = mean_nbrs(h1)  (half2 lanes) ----
__global__ __launch_bounds__(256) void k_agg2(
        const __half* __restrict__ h1,
        const int* __restrict__ deg, const unsigned short* __restrict__ nbr,
        __half* __restrict__ agg2) {
    const int t = blockIdx.x * 256 + threadIdx.x;
    if (t >= N_NODES * 8) return;
    const int node = t >> 3, fp = t & 7;
    int c = deg[node];
    float inv = c > 0 ? 1.f / (float)c : 1.f;
    int cc = c > MAXD ? MAXD : c;
    const unsigned short* np = nbr + (node << 6);
    float2 a0 = {0.f, 0.f}, a1 = {0.f, 0.f}, a2 = {0.f, 0.f}, a3 = {0.f, 0.f};
    int j = 0;
    for (; j + 4 <= cc; j += 4) {
        float2 v0 = __half22float2(*(const __half2*)(h1 + (np[j + 0] << 4) + (fp << 1)));
        float2 v1 = __half22float2(*(const __half2*)(h1 + (np[j + 1] << 4) + (fp << 1)));
        float2 v2 = __half22float2(*(const __half2*)(h1 + (np[j + 2] << 4) + (fp << 1)));
        float2 v3 = __half22float2(*(const __half2*)(h1 + (np[j + 3] << 4) + (fp << 1)));
        a0.x += v0.x; a0.y += v0.y; a1.x += v1.x; a1.y += v1.y;
        a2.x += v2.x; a2.y += v2.y; a3.x += v3.x; a3.y += v3.y;
    }
    for (; j < cc; ++j) {
        float2 v = __half22float2(*(const __half2*)(h1 + (np[j] << 4) + (fp << 1)));
        a0.x += v.x; a0.y += v.y;
    }
    *(__half2*)(agg2 + (node << 4) + (fp << 1)) =
        __floats2half2_rn((a0.x + a1.x + a2.x + a3.x) * inv,
                          (a0.y + a1.y + a2.y + a3.y) * inv);
}

// ---- K7 (k_head, MFMA): SAGE2 + MLP head, transposed D[out][node] ----
// wave = 16 nodes. Weights = A-op (transposed f16 LDS). Activations = B-op.
// C/D: col = lane&15 = node, row = (lane>>4)*4 + r = out-feat.
// B-frag: col = lane&15 = node, k = (lane>>4)*8 + e  -> same node per lane,
// so layer handoff is 8 shfl + cvt_pkrtz per frag (no LDS transpose).
__global__ __launch_bounds__(256) void k_head(
        const __half* __restrict__ h1, const __half* __restrict__ agg2,
        const float* __restrict__ w2n, const float* __restrict__ w2r,
        const float* __restrict__ b2,
        const float* __restrict__ fw1, const float* __restrict__ fb1,
        const float* __restrict__ fw2, const float* __restrict__ fb2,
        const float* __restrict__ fw3, const float* __restrict__ fb3,
        float* __restrict__ out) {
    __shared__ __align__(16) __half s_w2t[32 * 40];     // [out 32][k 32 pad 40]
    __shared__ __align__(16) __half s_fw1t[64 * 40];    // [out 64][k 32 pad 40]
    __shared__ __align__(16) __half s_fw2t[128 * 72];   // [out 128][k 64 pad 72]

    const int tid = threadIdx.x;
    for (int i = tid; i < 1024; i += 256) {
        int o = i & 31, k = i >> 5;
        float v = (k < 16) ? w2n[k * 32 + o] : w2r[(k - 16) * 32 + o];
        s_w2t[o * 40 + k] = __float2half(v);
    }
    for (int i = tid; i < 2048; i += 256) {
        int o = i & 63, k = i >> 6;
        s_fw1t[o * 40 + k] = __float2half(fw1[k * 64 + o]);
    }
    for (int i = tid; i < 8192; i += 256) {
        int o = i & 127, k = i >> 7;
        s_fw2t[o * 72 + k] = __float2half(fw2[k * 128 + o]);
    }
    __syncthreads();

    const int l = tid & 63, li = l & 15, g = l >> 4;
    const int wid = tid >> 6;
    const int node = blockIdx.x * 64 + wid * 16 + li;
    const int nodec = node < N_NODES ? node : N_NODES - 1;
    const int sl0 = li + 32 * (g & 1), sl1 = sl0 + 16;   // shfl sources
    const int tsel = g >> 1;

    // z B-frag: k<16 = agg2[node][0..15], k>=16 = h1[node][0..15] (fp16 direct)
    H8 Bz;
    {
        const __half* zb = (g < 2) ? agg2 : h1;
        Bz.v = *(const uint4*)(zb + (nodec << 4) + ((g & 1) << 3));
    }

    // ---- h2 = relu(z @ W2cat + b2): 2 M-tiles, K=32 ----
    unsigned int p01[2], p23[2];
#pragma unroll
    for (int t = 0; t < 2; ++t) {
        f32x4 c = *(const f32x4*)(b2 + 16 * t + 4 * g);
        H8 A; A.v = *(const uint4*)(s_w2t + (16 * t + li) * 40 + 8 * g);
        c = MM(A, Bz, c);
        p01[t] = pkh(fmaxf(c[0], 0.f), fmaxf(c[1], 0.f));
        p23[t] = pkh(fmaxf(c[2], 0.f), fmaxf(c[3], 0.f));
    }
    H8 Bh2;
    {
        unsigned int a, b;
        a = __shfl((int)p01[0], sl0); b = __shfl((int)p01[1], sl0); Bh2.u[0] = tsel ? b : a;
        a = __shfl((int)p23[0], sl0); b = __shfl((int)p23[1], sl0); Bh2.u[1] = tsel ? b : a;
        a = __shfl((int)p01[0], sl1); b = __shfl((int)p01[1], sl1); Bh2.u[2] = tsel ? b : a;
        a = __shfl((int)p23[0], sl1); b = __shfl((int)p23[1], sl1); Bh2.u[3] = tsel ? b : a;
    }

    // ---- h3 = relu(h2 @ fw1 + fb1): 4 M-tiles, K=32 ----
    unsigned int q01[4], q23[4];
#pragma unroll
    for (int t = 0; t < 4; ++t) {
        f32x4 c = *(const f32x4*)(fb1 + 16 * t + 4 * g);
        H8 A; A.v = *(const uint4*)(s_fw1t + (16 * t + li) * 40 + 8 * g);
        c = MM(A, Bh2, c);
        q01[t] = pkh(fmaxf(c[0], 0.f), fmaxf(c[1], 0.f));
        q23[t] = pkh(fmaxf(c[2], 0.f), fmaxf(c[3], 0.f));
    }
    H8 Bh3[2];
#pragma unroll
    for (int s = 0; s < 2; ++s) {
        unsigned int a, b;
        a = __shfl((int)q01[2 * s], sl0); b = __shfl((int)q01[2 * s + 1], sl0); Bh3[s].u[0] = tsel ? b : a;
        a = __shfl((int)q23[2 * s], sl0); b = __shfl((int)q23[2 * s + 1], sl0); Bh3[s].u[1] = tsel ? b : a;
        a = __shfl((int)q01[2 * s], sl1); b = __shfl((int)q01[2 * s + 1], sl1); Bh3[s].u[2] = tsel ? b : a;
        a = __shfl((int)q23[2 * s], sl1); b = __shfl((int)q23[2 * s + 1], sl1); Bh3[s].u[3] = tsel ? b : a;
    }

    // ---- h4 = relu(h3 @ fw2 + fb2); out = h4 @ fw3: 8 M-tiles, K=64 ----
    float o0 = 0.f, o1 = 0.f;
#pragma unroll
    for (int m = 0; m < 8; ++m) {
        f32x4 c = *(const f32x4*)(fb2 + 16 * m + 4 * g);
        H8 A;
        A.v = *(const uint4*)(s_fw2t + (16 * m + li) * 72 + 8 * g);
        c = MM(A, Bh3[0], c);
        A.v = *(const uint4*)(s_fw2t + (16 * m + li) * 72 + 32 + 8 * g);
        c = MM(A, Bh3[1], c);
        const float4* wp = (const float4*)(fw3 + (16 * m + 4 * g) * 2);
        float4 wA = wp[0], wB = wp[1];
        float r0 = fmaxf(c[0], 0.f), r1 = fmaxf(c[1], 0.f);
        float r2 = fmaxf(c[2], 0.f), r3 = fmaxf(c[3], 0.f);
        o0 += r0 * wA.x + r1 * wA.z + r2 * wB.x + r3 * wB.z;
        o1 += r0 * wA.y + r1 * wA.w + r2 * wB.y + r3 * wB.w;
    }
    o0 += __shfl_xor(o0, 16); o0 += __shfl_xor(o0, 32);
    o1 += __shfl_xor(o1, 16); o1 += __shfl_xor(o1, 32);
    if (g == 0 && node < N_NODES) {
        float2 r; r.x = o0 + fb3[0]; r.y = o1 + fb3[1];
        *(float2*)(out + node * 2) = r;
    }
}

extern "C" void kernel_launch(void* const* d_in, const int* in_sizes, int n_in,
                              void* d_out, int out_size, void* d_ws, size_t ws_size,
                              hipStream_t stream) {
    const float* x   = (const float*)d_in[0];
    const int*   ei  = (const int*)d_in[1];
    const int*   src = ei;
    const int*   dst = ei + N_EDGES;
    const float* w1n = (const float*)d_in[2];
    const float* w1r = (const float*)d_in[3];
    const float* b1  = (const float*)d_in[4];
    const float* w2n = (const float*)d_in[5];
    const float* w2r = (const float*)d_in[6];
    const float* b2  = (const float*)d_in[7];
    const float* fw1 = (const float*)d_in[8];
    const float* fb1 = (const float*)d_in[9];
    const float* fw2 = (const float*)d_in[10];
    const float* fb2 = (const float*)d_in[11];
    const float* fw3 = (const float*)d_in[12];
    const float* fb3 = (const float*)d_in[13];
    float* out = (float*)d_out;

    // workspace layout (~18.6 MB)
    unsigned int*   nbrU        = (unsigned int*)d_ws;              // 50000*32 uints (6.4MB)
    int*            deg         = (int*)(nbrU + N_NODES * 32);      // 50000
    __half*         xw1n        = (__half*)(deg + N_NODES);         // 800000
    __half*         xr1b        = xw1n + N_EDGES;                   // 800000
    __half*         h1          = xr1b + N_EDGES;                   // 800000
    __half*         agg2        = h1 + N_EDGES;                     // 800000
    unsigned int*   staging     = (unsigned int*)(agg2 + N_EDGES);  // 800000 (3.2MB)
    int*            ghist       = (int*)(staging + N_EDGES);        // 50048
    int*            gscan       = ghist + NENT;                     // 50048
    int*            part        = gscan + NENT;                     // 50048
    int*            blockSums   = part + NENT;                      // 196
    int*            bucketStart = blockSums + SCB;                  // 392

    const unsigned short* nbr = (const unsigned short*)nbrU;

    k_lin1<<<(N_NODES + 63) / 64, 256, 0, stream>>>(x, w1n, w1r, b1, xw1n, xr1b);
    k_hist<<<NSCB, 256, 0, stream>>>(dst, ghist);
    k_scanA<<<SCB, 256, 0, stream>>>(ghist, part, blockSums);
    k_scanB<<<1, 256, 0, stream>>>(blockSums);
    k_scanC<<<SCB, 256, 0, stream>>>(part, blockSums, gscan, bucketStart);
    k_scatter<<<NSCB, 256, 0, stream>>>(src, dst, gscan, staging);
    k_build<<<NBUCKET, 256, 0, stream>>>(staging, bucketStart, nbrU, deg);
    k_agg1<<<(N_NODES * 8 + 255) / 256, 256, 0, stream>>>(xw1n, xr1b, deg, nbr, h1);
    k_agg2<<<(N_NODES * 8 + 255) / 256, 256, 0, stream>>>(h1, deg, nbr, agg2);
    k_head<<<(N_NODES + 63) / 64, 256, 0, stream>>>(h1, agg2, w2n, w2r, b2,
                                                    fw1, fb1, fw2, fb2, fw3, fb3, out);
}